// Round 14
// baseline (1174.952 us; speedup 1.0000x reference)
//
#include <hip/hip_runtime.h>
#include <math.h>

#define IMGD 224
#define HW 50176      // 224*224
#define NK 100
#define NB 8
#define OUT_PER_B 76800   // 100*16*16*3 = 300*256
#define NCHUNK 131        // OpenBLAS k-blocking of 50176: 129x384, 320, 320

// partials layout: chunk-major [b][c][k*6+j] -> each block writes 600(or 1200)
// CONTIGUOUS floats. R12 lesson: strided per-(k,j) columns + __threadfence
// flushed 600 lines/block to HBM (19.7 MB/iter). Chunk-major flushes ~2.5 MB.
#define PART(b, c, u) ((size_t)((b) * NCHUNK + (c)) * 600 + (u))

// ratio = 10.0 / sqrt(224*224/100) in f64, rounded to f32 when numpy multiplies
// the f32 arange arrays by the weak python scalar.
static __device__ __forceinline__ float ratio_f32() {
  return (float)(10.0 / sqrt(224.0 * 224.0 / 100.0));
}

// distance op sequence — the single source of truth for bit-exactness:
// dot = fmul(f0,c0); fma(f1,c1); fma(f2,c2); fma(f3,c3); fma(f4,c4)
// d   = fsub(fadd(fsq, c2k), fmul(2, dot))
static __device__ __forceinline__ float dist5s(float f0, float f1, float f2,
                                               float f3, float f4, float fsq,
                                               float c0, float c1, float c2,
                                               float c3, float c4, float q) {
  float dot = __fmul_rn(f0, c0);
  dot = __fmaf_rn(f1, c1, dot);
  dot = __fmaf_rn(f2, c2, dot);
  dot = __fmaf_rn(f3, c3, dot);
  dot = __fmaf_rn(f4, c4, dot);
  return __fsub_rn(__fadd_rn(fsq, q), __fmul_rn(2.0f, dot));
}

// fsq = np.sum(feat*feat): rounded products, sequential adds, no FMA
static __device__ __forceinline__ float fsq5(float f0, float f1, float f2,
                                             float f3, float f4) {
  float s = __fmul_rn(f0, f0);
  s = __fadd_rn(s, __fmul_rn(f1, f1));
  s = __fadd_rn(s, __fmul_rn(f2, f2));
  s = __fadd_rn(s, __fmul_rn(f3, f3));
  s = __fadd_rn(s, __fmul_rn(f4, f4));
  return s;
}

// ---------- setup: blocks 0..15 build A; blocks 16..23 init centers+c2+counters ----------
__global__ void __launch_bounds__(256) setup_kernel(
    const float* __restrict__ x, float* __restrict__ A,
    float* __restrict__ centers, float* __restrict__ c2g,
    int* __restrict__ counters) {
  int blk = blockIdx.x;
  int tid = threadIdx.x;
  if (blk < 16) {
    // resize matrix A[16][224], jax linear+antialias semantics
    __shared__ float red[256];
    int p = blk;
    float tri = 0.0f;
    if (tid < IMGD) {
      float center = (p + 0.5f) * 14.0f - 0.5f;
      float xd = fabsf(center - (float)tid) / 14.0f;
      tri = fmaxf(0.0f, 1.0f - xd);
    }
    red[tid] = tri;
    __syncthreads();
    for (int s = 128; s > 0; s >>= 1) {
      if (tid < s) red[tid] += red[tid + s];
      __syncthreads();
    }
    float Z = red[0];
    if (tid < IMGD) A[p * IMGD + tid] = tri / Z;
  } else {
    int b = blk - 16;
    if (tid == 0) counters[b] = 0;
    int k = tid;
    if (k >= NK) return;
    int gy = k / 10, gx = k % 10;
    int cy = (int)((gy + 0.5) * 224.0 / 10.0);  // trunc like .astype(int32)
    int cx = (int)((gx + 0.5) * 224.0 / 10.0);
    int i = cy * IMGD + cx;
    const float ratio = ratio_f32();
    float c0 = x[((size_t)b * 3 + 0) * HW + i];
    float c1 = x[((size_t)b * 3 + 1) * HW + i];
    float c2 = x[((size_t)b * 3 + 2) * HW + i];
    float c3 = __fmul_rn((float)cy, ratio);
    float c4 = __fmul_rn((float)cx, ratio);
    float* c = centers + ((size_t)b * NK + k) * 5;
    c[0] = c0; c[1] = c1; c[2] = c2; c[3] = c3; c[4] = c4;
    // c2 = np.sum(centers*centers): rounded products, sequential adds
    float s = __fmul_rn(c0, c0);
    s = __fadd_rn(s, __fmul_rn(c1, c1));
    s = __fadd_rn(s, __fmul_rn(c2, c2));
    s = __fadd_rn(s, __fmul_rn(c3, c3));
    s = __fadd_rn(s, __fmul_rn(c4, c4));
    c2g[(size_t)b * NK + k] = s;
  }
}

// ---------- fused iteration: 2 chunks/block + last-block combine ----------
// 256 thr x 3 px = 768 px = 2 OpenBLAS chunks (halves LDS center traffic per
// px vs 128-thr blocks). Per-(k,chunk) add chains ascending-pixel via stable
// counting-sort value compaction. Last-arriving block per b (device-scope
// counter, R12-proven protocol) runs the ascending-chunk combine + update.
__global__ void __launch_bounds__(256) iter_kernel(
    const float* __restrict__ x, float* __restrict__ centers,
    float* __restrict__ c2g, float* __restrict__ partials,
    int* __restrict__ counters) {
  __shared__ float4 ckp[150];               // pair-packed centers: 3 float4 / 2 k
  __shared__ unsigned int mask[2 * NK * 12];
  __shared__ unsigned short ppk[2 * NK * 12];
  __shared__ float4 cval4[768];
  __shared__ float  cvalf[768];
  __shared__ int cnt[256];
  __shared__ int offx[256];
  __shared__ int wsum[4];
  __shared__ int lastFlag;
  __shared__ float sums[600];
  int blk = blockIdx.x;   // 0..65
  int b = blockIdx.y;
  int tid = threadIdx.x;
  int c0 = 2 * blk;
  bool has2 = (c0 < 130);
  int len0 = (c0 < 129) ? 384 : 320;
  int start0 = (c0 < 129) ? c0 * 384 : 49536 + (c0 - 129) * 320;
  int c1 = c0 + 1;
  int len1 = has2 ? ((c1 < 129) ? 384 : 320) : 0;
  int start1 = has2 ? ((c1 < 129) ? c1 * 384 : 49536 + (c1 - 129) * 320) : 0;
  int superlen = len0 + len1;

  const float* cb = centers + (size_t)b * NK * 5;
  const float* c2b = c2g + (size_t)b * NK;
  for (int t = tid; t < 150; t += 256) {
    int p = t / 3, r = t - 3 * p;
    int k0 = 2 * p, k1 = 2 * p + 1;
    float4 v;
    if (r == 0)      v = make_float4(cb[k0*5+0], cb[k0*5+1], cb[k0*5+2], cb[k0*5+3]);
    else if (r == 1) v = make_float4(cb[k0*5+4], c2b[k0],    cb[k1*5+0], cb[k1*5+1]);
    else             v = make_float4(cb[k1*5+2], cb[k1*5+3], cb[k1*5+4], c2b[k1]);
    ckp[t] = v;
  }
  for (int t = tid; t < 2 * NK * 12; t += 256) mask[t] = 0u;
  __syncthreads();

  const float* x0 = x + (size_t)b * 3 * HW;
  const float ratio = ratio_f32();

  // 3 px/thread over the superchunk: t = tid, tid+256, tid+512 (ascending)
  float f0[3], f1[3], f2[3], f3[3], f4[3], fq[3], best[3];
  int bk[3], tloc[3], chnk[3];
  bool vld[3];
  for (int r = 0; r < 3; ++r) {
    int t = tid + r * 256;
    vld[r] = (t < superlen);
    int ch = (t >= len0) ? 1 : 0;
    int tl = t - ch * len0;
    if (!vld[r]) { ch = 0; tl = 0; }
    chnk[r] = ch; tloc[r] = tl;
    int i = (ch ? start1 : start0) + tl;
    int y = i / IMGD, xw = i - y * IMGD;
    f0[r] = x0[i]; f1[r] = x0[HW + i]; f2[r] = x0[2 * HW + i];
    f3[r] = __fmul_rn((float)y, ratio);
    f4[r] = __fmul_rn((float)xw, ratio);
    fq[r] = fsq5(f0[r], f1[r], f2[r], f3[r], f4[r]);
    best[r] = 3.4e38f; bk[r] = 0;
  }
  for (int p = 0; p < 50; ++p) {   // k = 2p, 2p+1 ascending
    float4 v0 = ckp[3 * p], v1 = ckp[3 * p + 1], v2 = ckp[3 * p + 2];
    for (int r = 0; r < 3; ++r) {
      float d0 = dist5s(f0[r], f1[r], f2[r], f3[r], f4[r], fq[r],
                        v0.x, v0.y, v0.z, v0.w, v1.x, v1.y);
      if (d0 < best[r]) { best[r] = d0; bk[r] = 2 * p; }      // first-index wins
      float d1 = dist5s(f0[r], f1[r], f2[r], f3[r], f4[r], fq[r],
                        v1.z, v1.w, v2.x, v2.y, v2.z, v2.w);
      if (d1 < best[r]) { best[r] = d1; bk[r] = 2 * p + 1; }
    }
  }
  for (int r = 0; r < 3; ++r) {
    if (vld[r])
      atomicOr(&mask[chnk[r] * 1200 + bk[r] * 12 + (tloc[r] >> 5)],
               1u << (tloc[r] & 31));
  }
  __syncthreads();

  // per-(chunk,k) cumulative popcounts; u = chunk*100 + k
  int myCnt = 0;
  if (tid < 200) {
    int ch = tid / 100, k = tid - ch * 100;
    int s = 0;
    for (int g = 0; g < 12; ++g) {
      ppk[ch * 1200 + k * 12 + g] = (unsigned short)s;
      s += __popc(mask[ch * 1200 + k * 12 + g]);
    }
    myCnt = s;
  }
  cnt[tid] = myCnt;

  // inclusive prefix over 256 counts: shfl per wave + cross-wave fixup
  int v = myCnt;
  for (int d = 1; d < 64; d <<= 1) {
    int u = __shfl_up(v, d, 64);
    if ((tid & 63) >= d) v += u;
  }
  int wid = tid >> 6;
  if ((tid & 63) == 63) wsum[wid] = v;
  __syncthreads();
  if (wid >= 1) v += wsum[0];
  if (wid >= 2) v += wsum[1];
  if (wid >= 3) v += wsum[2];
  offx[tid] = v;
  __syncthreads();

  // stable VALUE scatter: chunk0 lands in [0,len0), chunk1 in [len0,superlen)
  for (int r = 0; r < 3; ++r) {
    if (vld[r]) {
      int u = chnk[r] * 100 + bk[r];
      int g = tloc[r] >> 5, j = tloc[r] & 31;
      unsigned int m = mask[chnk[r] * 1200 + bk[r] * 12 + g];
      int rank = ppk[chnk[r] * 1200 + bk[r] * 12 + g] +
                 __popc(m & ((1u << j) - 1u));
      int pos = offx[u] - cnt[u] + rank;
      cval4[pos] = make_float4(f0[r], f1[r], f2[r], f3[r]);
      cvalf[pos] = f4[r];
    }
  }
  __syncthreads();

  // scan: thread u walks its consecutive compacted range (ascending t),
  // writes 6 contiguous floats to chunk-major partials
  if (tid < 200 && (tid < 100 || has2)) {
    int ch = tid / 100, k = tid - ch * 100;
    int n = cnt[tid];
    int base = offx[tid] - n;
    float s0 = 0.f, s1 = 0.f, s2 = 0.f, s3 = 0.f, s4 = 0.f, s5 = 0.f;
    for (int m = 0; m < n; ++m) {
      float4 vv = cval4[base + m];
      float ww = cvalf[base + m];
      s0 = __fadd_rn(s0, vv.x);
      s1 = __fadd_rn(s1, vv.y);
      s2 = __fadd_rn(s2, vv.z);
      s3 = __fadd_rn(s3, vv.w);
      s4 = __fadd_rn(s4, ww);
      s5 += 1.0f;
    }
    int cc = ch ? c1 : c0;
    float* pp = partials + PART(b, cc, k * 6);
    pp[0] = s0; pp[1] = s1; pp[2] = s2; pp[3] = s3; pp[4] = s4; pp[5] = s5;
    __threadfence();   // release: contiguous lines -> small flush (R12 fix)
  }
  __syncthreads();
  if (tid == 0) {
    int old = atomicAdd(&counters[b], 1);   // device-scope
    lastFlag = ((old % 66) == 65) ? 1 : 0;
  }
  __syncthreads();
  if (!lastFlag) return;
  __threadfence();     // acquire: see all blocks' partials

  // combine: 600 chains (k*6+j), ascending chunk order = ref blocked sum
  if (tid < 200) {
    for (int v2 = tid; v2 < 600; v2 += 200) {
      float s = partials[PART(b, 0, v2)];
      for (int cc = 1; cc < NCHUNK; ++cc)
        s = __fadd_rn(s, partials[PART(b, cc, v2)]);
      sums[v2] = s;
    }
  }
  __syncthreads();
  if (tid < NK) {
    float cntv = sums[tid * 6 + 5];
    float* cc2 = centers + ((size_t)b * NK + tid) * 5;
    float n0, n1, n2, n3, n4;
    if (cntv > 0.0f) {               // where(cnt>0, new, centers)
      float m = fmaxf(cntv, 1.0f);   // np.maximum(cnt,1.0): exact int in f32
      n0 = __fdiv_rn(sums[tid * 6 + 0], m);
      n1 = __fdiv_rn(sums[tid * 6 + 1], m);
      n2 = __fdiv_rn(sums[tid * 6 + 2], m);
      n3 = __fdiv_rn(sums[tid * 6 + 3], m);
      n4 = __fdiv_rn(sums[tid * 6 + 4], m);
      cc2[0] = n0; cc2[1] = n1; cc2[2] = n2; cc2[3] = n3; cc2[4] = n4;
    } else {
      n0 = cc2[0]; n1 = cc2[1]; n2 = cc2[2]; n3 = cc2[3]; n4 = cc2[4];
    }
    // c2 = sum(centers*centers): rounded products, sequential adds
    float t0 = __fmul_rn(n0, n0);
    t0 = __fadd_rn(t0, __fmul_rn(n1, n1));
    t0 = __fadd_rn(t0, __fmul_rn(n2, n2));
    t0 = __fadd_rn(t0, __fmul_rn(n3, n3));
    t0 = __fadd_rn(t0, __fmul_rn(n4, n4));
    c2g[(size_t)b * NK + tid] = t0;
  }
  // centers/c2g updates become visible at the kernel boundary (cheap
  // coherence point) before the next iter dispatch reads them.
}

// ---------- final full-image assignment: 2 px/thread, k-batched by 4 ----------
__global__ void __launch_bounds__(256) assign_kernel(
    const float* __restrict__ x, const float* __restrict__ centers,
    const float* __restrict__ c2g, int* __restrict__ labels) {
  __shared__ float4 ck4[NK];
  __shared__ float2 ck2[NK];
  int b = blockIdx.y;
  int tid = threadIdx.x;
  int base = blockIdx.x * 512;   // grid.x = 98 -> 98*512 = 50176 exact

  const float* cb = centers + (size_t)b * NK * 5;
  const float* c2b = c2g + (size_t)b * NK;
  for (int k = tid; k < NK; k += 256) {
    ck4[k] = make_float4(cb[k * 5 + 0], cb[k * 5 + 1], cb[k * 5 + 2], cb[k * 5 + 3]);
    ck2[k] = make_float2(cb[k * 5 + 4], c2b[k]);
  }
  __syncthreads();

  const float* x0 = x + (size_t)b * 3 * HW;
  const float ratio = ratio_f32();
  float f0[2], f1[2], f2[2], f3[2], f4[2], fq[2];
  float best[2]; int bk[2];
  for (int r = 0; r < 2; ++r) {
    int i = base + r * 256 + tid;   // coalesced
    int y = i / IMGD, xw = i - y * IMGD;
    f0[r] = x0[i]; f1[r] = x0[HW + i]; f2[r] = x0[2 * HW + i];
    f3[r] = __fmul_rn((float)y, ratio);
    f4[r] = __fmul_rn((float)xw, ratio);
    fq[r] = fsq5(f0[r], f1[r], f2[r], f3[r], f4[r]);
    best[r] = 3.4e38f; bk[r] = 0;
  }
  for (int kb = 0; kb < NK; kb += 4) {
    float4 a4[4]; float2 a2[4];
    for (int kk = 0; kk < 4; ++kk) { a4[kk] = ck4[kb + kk]; a2[kk] = ck2[kb + kk]; }
    for (int kk = 0; kk < 4; ++kk) {
      for (int r = 0; r < 2; ++r) {
        float d = dist5s(f0[r], f1[r], f2[r], f3[r], f4[r], fq[r],
                         a4[kk].x, a4[kk].y, a4[kk].z, a4[kk].w, a2[kk].x, a2[kk].y);
        if (d < best[r]) { best[r] = d; bk[r] = kb + kk; }  // first-index wins
      }
    }
  }
  int* lb = labels + (size_t)b * HW;
  for (int r = 0; r < 2; ++r) lb[base + r * 256 + tid] = bk[r];
}

// ---------- embed: block = (b,p,q); LDS bins per (k,c); direct stores ----------
__global__ void __launch_bounds__(256) embed_kernel(
    const float* __restrict__ x, const int* __restrict__ labels,
    const float* __restrict__ A, float* __restrict__ out) {
  __shared__ float sk[NK * 3];
  int b = blockIdx.y;
  int p = blockIdx.x >> 4;
  int q = blockIdx.x & 15;
  int tid = threadIdx.x;
  for (int t = tid; t < NK * 3; t += 256) sk[t] = 0.0f;
  __syncthreads();

  // A[p,h] support: h in [14p-7, 14p+20] clipped
  int h0 = max(0, 14 * p - 7), h1 = min(IMGD - 1, 14 * p + 20);
  int w0 = max(0, 14 * q - 7), w1 = min(IMGD - 1, 14 * q + 20);
  int hl = h1 - h0 + 1, wl = w1 - w0 + 1;
  int n = hl * wl;

  const float* xb = x + (size_t)b * 3 * HW;
  const int* lb = labels + (size_t)b * HW;
  const float* Ap = A + p * IMGD;
  const float* Aq = A + q * IMGD;

  for (int idx = tid; idx < n; idx += 256) {
    int dh = idx / wl;
    int hh = h0 + dh;
    int ww = w0 + (idx - dh * wl);
    int i = hh * IMGD + ww;
    float wgt = Ap[hh] * Aq[ww];
    int k = lb[i];
    atomicAdd(&sk[k * 3 + 0], wgt * xb[i]);
    atomicAdd(&sk[k * 3 + 1], wgt * xb[HW + i]);
    atomicAdd(&sk[k * 3 + 2], wgt * xb[2 * HW + i]);
  }
  __syncthreads();

  float* outb = out + (size_t)b * OUT_PER_B;
  int base = p * 48 + q * 3;
  for (int t = tid; t < NK * 3; t += 256) {
    int k = t / 3, c = t - 3 * k;
    int f = k * 768 + base + c;           // flat [K,P,P,C] index
    outb[(f & 255) * 300 + (f >> 8)] = sk[t];  // view(B,300,256) + transpose
  }
}

extern "C" void kernel_launch(void* const* d_in, const int* in_sizes, int n_in,
                              void* d_out, int out_size, void* d_ws, size_t ws_size,
                              hipStream_t stream) {
  const float* x = (const float*)d_in[0];
  float* out = (float*)d_out;
  char* ws = (char*)d_ws;
  // ws layout:
  float* A        = (float*)(ws);              // 14336 B
  float* centers  = (float*)(ws + 16384);      // 16000 B
  float* c2g      = (float*)(ws + 49152);      // 3200 B
  int*   labels   = (int*)(ws + 90112);        // 1605632 B
  float* partials = (float*)(ws + 1703936);    // 8*131*600*4 = 2515200 B
  int*   counters = (int*)(ws + 4220928);      // 8 ints

  setup_kernel<<<24, 256, 0, stream>>>(x, A, centers, c2g, counters);

  dim3 cgrid(66, NB);             // 66 blocks x 2 chunks = 131 chunks (+tail)
  for (int it = 0; it < 10; ++it) {
    iter_kernel<<<cgrid, 256, 0, stream>>>(x, centers, c2g, partials, counters);
  }
  dim3 agrid(98, NB);             // 98*512 = 50176 exact
  assign_kernel<<<agrid, 256, 0, stream>>>(x, centers, c2g, labels);

  dim3 egrid(256, NB);            // (p*16+q) x b
  embed_kernel<<<egrid, 256, 0, stream>>>(x, labels, A, out);
}

// Round 15
// 366.608 us; speedup vs baseline: 3.2049x; 3.2049x over previous
//
#include <hip/hip_runtime.h>
#include <math.h>

#define IMGD 224
#define HW 50176      // 224*224
#define NK 100
#define NB 8
#define OUT_PER_B 76800   // 100*16*16*3 = 300*256
#define NCHUNK 131        // OpenBLAS k-blocking of 50176: 129x384, 320, 320

// partials layout: k-major [b][k][j][c]. NO intra-kernel fence -> scattered
// stores coalesce in L2 (R11: WRITE_SIZE == buffer size, no amplification),
// and combine reads 786 contiguous floats per (b,k).
// R12/R14 lesson: per-block device-scope fences serialize ~1.2-1.7 us of L2
// writeback EACH on gfx950 -> never reduce across blocks inside a kernel.

// ratio = 10.0 / sqrt(224*224/100) in f64, rounded to f32 when numpy multiplies
// the f32 arange arrays by the weak python scalar.
static __device__ __forceinline__ float ratio_f32() {
  return (float)(10.0 / sqrt(224.0 * 224.0 / 100.0));
}

// distance op sequence — the single source of truth for bit-exactness:
// dot = fmul(f0,c0); fma(f1,c1); fma(f2,c2); fma(f3,c3); fma(f4,c4)
// d   = fsub(fadd(fsq, c2k), fmul(2, dot))
static __device__ __forceinline__ float dist5s(float f0, float f1, float f2,
                                               float f3, float f4, float fsq,
                                               float c0, float c1, float c2,
                                               float c3, float c4, float q) {
  float dot = __fmul_rn(f0, c0);
  dot = __fmaf_rn(f1, c1, dot);
  dot = __fmaf_rn(f2, c2, dot);
  dot = __fmaf_rn(f3, c3, dot);
  dot = __fmaf_rn(f4, c4, dot);
  return __fsub_rn(__fadd_rn(fsq, q), __fmul_rn(2.0f, dot));
}

// fsq = np.sum(feat*feat): rounded products, sequential adds, no FMA
static __device__ __forceinline__ float fsq5(float f0, float f1, float f2,
                                             float f3, float f4) {
  float s = __fmul_rn(f0, f0);
  s = __fadd_rn(s, __fmul_rn(f1, f1));
  s = __fadd_rn(s, __fmul_rn(f2, f2));
  s = __fadd_rn(s, __fmul_rn(f3, f3));
  s = __fadd_rn(s, __fmul_rn(f4, f4));
  return s;
}

// ---------- setup: blocks 0..15 build A; blocks 16..23 init centers+c2 ----------
__global__ void __launch_bounds__(256) setup_kernel(
    const float* __restrict__ x, float* __restrict__ A,
    float* __restrict__ centers, float* __restrict__ c2g) {
  int blk = blockIdx.x;
  int tid = threadIdx.x;
  if (blk < 16) {
    // resize matrix A[16][224], jax linear+antialias semantics
    __shared__ float red[256];
    int p = blk;
    float tri = 0.0f;
    if (tid < IMGD) {
      float center = (p + 0.5f) * 14.0f - 0.5f;
      float xd = fabsf(center - (float)tid) / 14.0f;
      tri = fmaxf(0.0f, 1.0f - xd);
    }
    red[tid] = tri;
    __syncthreads();
    for (int s = 128; s > 0; s >>= 1) {
      if (tid < s) red[tid] += red[tid + s];
      __syncthreads();
    }
    float Z = red[0];
    if (tid < IMGD) A[p * IMGD + tid] = tri / Z;
  } else {
    int b = blk - 16;
    int k = tid;
    if (k >= NK) return;
    int gy = k / 10, gx = k % 10;
    int cy = (int)((gy + 0.5) * 224.0 / 10.0);  // trunc like .astype(int32)
    int cx = (int)((gx + 0.5) * 224.0 / 10.0);
    int i = cy * IMGD + cx;
    const float ratio = ratio_f32();
    float c0 = x[((size_t)b * 3 + 0) * HW + i];
    float c1 = x[((size_t)b * 3 + 1) * HW + i];
    float c2 = x[((size_t)b * 3 + 2) * HW + i];
    float c3 = __fmul_rn((float)cy, ratio);
    float c4 = __fmul_rn((float)cx, ratio);
    float* c = centers + ((size_t)b * NK + k) * 5;
    c[0] = c0; c[1] = c1; c[2] = c2; c[3] = c3; c[4] = c4;
    // c2 = np.sum(centers*centers): rounded products, sequential adds
    float s = __fmul_rn(c0, c0);
    s = __fadd_rn(s, __fmul_rn(c1, c1));
    s = __fadd_rn(s, __fmul_rn(c2, c2));
    s = __fadd_rn(s, __fmul_rn(c3, c3));
    s = __fadd_rn(s, __fmul_rn(c4, c4));
    c2g[(size_t)b * NK + k] = s;
  }
}

// ---------- fused assign+partial: 2 chunks per 256-thread block ----------
// 256 thr x 3 px = 768 px = 2 OpenBLAS chunks (halves LDS center traffic per
// px vs 128-thr blocks). Per-(k,chunk) add chains ascending-pixel via stable
// counting-sort value compaction (bit-identical to sequential blocked sgemm).
// NO cross-block combine, NO fences: kernel boundary is the coherence point.
__global__ void __launch_bounds__(256) iter_kernel(
    const float* __restrict__ x, const float* __restrict__ centers,
    const float* __restrict__ c2g, float* __restrict__ partials) {
  __shared__ float4 ckp[150];               // pair-packed centers: 3 float4 / 2 k
  __shared__ unsigned int mask[2 * NK * 12];
  __shared__ unsigned short ppk[2 * NK * 12];
  __shared__ float4 cval4[768];
  __shared__ float  cvalf[768];
  __shared__ int cnt[256];
  __shared__ int offx[256];
  __shared__ int wsum[4];
  int blk = blockIdx.x;   // 0..65
  int b = blockIdx.y;
  int tid = threadIdx.x;
  int c0 = 2 * blk;
  bool has2 = (c0 < 130);
  int len0 = (c0 < 129) ? 384 : 320;
  int start0 = (c0 < 129) ? c0 * 384 : 49536 + (c0 - 129) * 320;
  int c1 = c0 + 1;
  int len1 = has2 ? ((c1 < 129) ? 384 : 320) : 0;
  int start1 = has2 ? ((c1 < 129) ? c1 * 384 : 49536 + (c1 - 129) * 320) : 0;
  int superlen = len0 + len1;

  const float* cb = centers + (size_t)b * NK * 5;
  const float* c2b = c2g + (size_t)b * NK;
  for (int t = tid; t < 150; t += 256) {
    int p = t / 3, r = t - 3 * p;
    int k0 = 2 * p, k1 = 2 * p + 1;
    float4 v;
    if (r == 0)      v = make_float4(cb[k0*5+0], cb[k0*5+1], cb[k0*5+2], cb[k0*5+3]);
    else if (r == 1) v = make_float4(cb[k0*5+4], c2b[k0],    cb[k1*5+0], cb[k1*5+1]);
    else             v = make_float4(cb[k1*5+2], cb[k1*5+3], cb[k1*5+4], c2b[k1]);
    ckp[t] = v;
  }
  for (int t = tid; t < 2 * NK * 12; t += 256) mask[t] = 0u;
  __syncthreads();

  const float* x0 = x + (size_t)b * 3 * HW;
  const float ratio = ratio_f32();

  // 3 px/thread over the superchunk: t = tid, tid+256, tid+512 (ascending)
  float f0[3], f1[3], f2[3], f3[3], f4[3], fq[3], best[3];
  int bk[3], tloc[3], chnk[3];
  bool vld[3];
  for (int r = 0; r < 3; ++r) {
    int t = tid + r * 256;
    vld[r] = (t < superlen);
    int ch = (t >= len0) ? 1 : 0;
    int tl = t - ch * len0;
    if (!vld[r]) { ch = 0; tl = 0; }
    chnk[r] = ch; tloc[r] = tl;
    int i = (ch ? start1 : start0) + tl;
    int y = i / IMGD, xw = i - y * IMGD;
    f0[r] = x0[i]; f1[r] = x0[HW + i]; f2[r] = x0[2 * HW + i];
    f3[r] = __fmul_rn((float)y, ratio);
    f4[r] = __fmul_rn((float)xw, ratio);
    fq[r] = fsq5(f0[r], f1[r], f2[r], f3[r], f4[r]);
    best[r] = 3.4e38f; bk[r] = 0;
  }
  for (int p = 0; p < 50; ++p) {   // k = 2p, 2p+1 ascending
    float4 v0 = ckp[3 * p], v1 = ckp[3 * p + 1], v2 = ckp[3 * p + 2];
    for (int r = 0; r < 3; ++r) {
      float d0 = dist5s(f0[r], f1[r], f2[r], f3[r], f4[r], fq[r],
                        v0.x, v0.y, v0.z, v0.w, v1.x, v1.y);
      if (d0 < best[r]) { best[r] = d0; bk[r] = 2 * p; }      // first-index wins
      float d1 = dist5s(f0[r], f1[r], f2[r], f3[r], f4[r], fq[r],
                        v1.z, v1.w, v2.x, v2.y, v2.z, v2.w);
      if (d1 < best[r]) { best[r] = d1; bk[r] = 2 * p + 1; }
    }
  }
  for (int r = 0; r < 3; ++r) {
    if (vld[r])
      atomicOr(&mask[chnk[r] * 1200 + bk[r] * 12 + (tloc[r] >> 5)],
               1u << (tloc[r] & 31));
  }
  __syncthreads();

  // per-(chunk,k) cumulative popcounts; u = chunk*100 + k
  int myCnt = 0;
  if (tid < 200) {
    int ch = tid / 100, k = tid - ch * 100;
    int s = 0;
    for (int g = 0; g < 12; ++g) {
      ppk[ch * 1200 + k * 12 + g] = (unsigned short)s;
      s += __popc(mask[ch * 1200 + k * 12 + g]);
    }
    myCnt = s;
  }
  cnt[tid] = myCnt;

  // inclusive prefix over 256 counts: shfl per wave + cross-wave fixup
  int v = myCnt;
  for (int d = 1; d < 64; d <<= 1) {
    int u = __shfl_up(v, d, 64);
    if ((tid & 63) >= d) v += u;
  }
  int wid = tid >> 6;
  if ((tid & 63) == 63) wsum[wid] = v;
  __syncthreads();
  if (wid >= 1) v += wsum[0];
  if (wid >= 2) v += wsum[1];
  if (wid >= 3) v += wsum[2];
  offx[tid] = v;
  __syncthreads();

  // stable VALUE scatter: chunk0 lands in [0,len0), chunk1 in [len0,superlen)
  for (int r = 0; r < 3; ++r) {
    if (vld[r]) {
      int u = chnk[r] * 100 + bk[r];
      int g = tloc[r] >> 5, j = tloc[r] & 31;
      unsigned int m = mask[chnk[r] * 1200 + bk[r] * 12 + g];
      int rank = ppk[chnk[r] * 1200 + bk[r] * 12 + g] +
                 __popc(m & ((1u << j) - 1u));
      int pos = offx[u] - cnt[u] + rank;
      cval4[pos] = make_float4(f0[r], f1[r], f2[r], f3[r]);
      cvalf[pos] = f4[r];
    }
  }
  __syncthreads();

  // scan: thread u walks its consecutive compacted range (ascending t)
  if (tid < 200 && (tid < 100 || has2)) {
    int ch = tid / 100, k = tid - ch * 100;
    int n = cnt[tid];
    int base = offx[tid] - n;
    float s0 = 0.f, s1 = 0.f, s2 = 0.f, s3 = 0.f, s4 = 0.f, s5 = 0.f;
    for (int m = 0; m < n; ++m) {
      float4 vv = cval4[base + m];
      float ww = cvalf[base + m];
      s0 = __fadd_rn(s0, vv.x);
      s1 = __fadd_rn(s1, vv.y);
      s2 = __fadd_rn(s2, vv.z);
      s3 = __fadd_rn(s3, vv.w);
      s4 = __fadd_rn(s4, ww);
      s5 += 1.0f;
    }
    // k-major layout [b][k][j][c]: combine reads contiguous
    int cc = ch ? c1 : c0;
    float* pp = partials + ((size_t)(b * NK + k) * 6) * NCHUNK + cc;
    pp[0 * NCHUNK] = s0; pp[1 * NCHUNK] = s1; pp[2 * NCHUNK] = s2;
    pp[3 * NCHUNK] = s3; pp[4 * NCHUNK] = s4; pp[5 * NCHUNK] = s5;
  }
}

// ---------- combine: one block per (b,k); LDS-staged 131-chains ----------
// 128 threads stage the 786 contiguous partials (parallel, coalesced); then
// 6 threads run the sequential ascending-chunk chains LDS-fed. Same add
// order as the blocked-sgemm reference.
__global__ void __launch_bounds__(128) combine_update_kernel(
    float* __restrict__ centers, const float* __restrict__ partials,
    float* __restrict__ c2g) {
  __shared__ float st[6 * NCHUNK];
  __shared__ float sums[6];
  __shared__ float newc[5];
  int bk = blockIdx.x;                 // b*NK + k
  int tid = threadIdx.x;
  const float* base = partials + (size_t)bk * 6 * NCHUNK;
  for (int t = tid; t < 6 * NCHUNK; t += 128) st[t] = base[t];
  __syncthreads();
  if (tid < 6) {
    const float* row = st + tid * NCHUNK;
    float s = row[0];                  // C = 0 + chunk0 (exact)
    for (int c = 1; c < NCHUNK; ++c) s = __fadd_rn(s, row[c]);
    sums[tid] = s;
  }
  __syncthreads();
  float cntv = sums[5];
  float* cc = centers + (size_t)bk * 5;
  if (tid < 5) {
    float v;
    if (cntv > 0.0f) {                 // where(cnt>0, new, centers)
      float m = fmaxf(cntv, 1.0f);     // np.maximum(cnt,1.0): exact int in f32
      v = __fdiv_rn(sums[tid], m);
      cc[tid] = v;
    } else {
      v = cc[tid];                     // unchanged center
    }
    newc[tid] = v;
  }
  __syncthreads();
  if (tid == 0) {
    // c2 = sum(centers*centers): rounded products, sequential adds
    float t0 = __fmul_rn(newc[0], newc[0]);
    t0 = __fadd_rn(t0, __fmul_rn(newc[1], newc[1]));
    t0 = __fadd_rn(t0, __fmul_rn(newc[2], newc[2]));
    t0 = __fadd_rn(t0, __fmul_rn(newc[3], newc[3]));
    t0 = __fadd_rn(t0, __fmul_rn(newc[4], newc[4]));
    c2g[bk] = t0;
  }
}

// ---------- final full-image assignment: 2 px/thread, k-batched by 4 ----------
__global__ void __launch_bounds__(256) assign_kernel(
    const float* __restrict__ x, const float* __restrict__ centers,
    const float* __restrict__ c2g, int* __restrict__ labels) {
  __shared__ float4 ck4[NK];
  __shared__ float2 ck2[NK];
  int b = blockIdx.y;
  int tid = threadIdx.x;
  int base = blockIdx.x * 512;   // grid.x = 98 -> 98*512 = 50176 exact

  const float* cb = centers + (size_t)b * NK * 5;
  const float* c2b = c2g + (size_t)b * NK;
  for (int k = tid; k < NK; k += 256) {
    ck4[k] = make_float4(cb[k * 5 + 0], cb[k * 5 + 1], cb[k * 5 + 2], cb[k * 5 + 3]);
    ck2[k] = make_float2(cb[k * 5 + 4], c2b[k]);
  }
  __syncthreads();

  const float* x0 = x + (size_t)b * 3 * HW;
  const float ratio = ratio_f32();
  float f0[2], f1[2], f2[2], f3[2], f4[2], fq[2];
  float best[2]; int bk[2];
  for (int r = 0; r < 2; ++r) {
    int i = base + r * 256 + tid;   // coalesced
    int y = i / IMGD, xw = i - y * IMGD;
    f0[r] = x0[i]; f1[r] = x0[HW + i]; f2[r] = x0[2 * HW + i];
    f3[r] = __fmul_rn((float)y, ratio);
    f4[r] = __fmul_rn((float)xw, ratio);
    fq[r] = fsq5(f0[r], f1[r], f2[r], f3[r], f4[r]);
    best[r] = 3.4e38f; bk[r] = 0;
  }
  for (int kb = 0; kb < NK; kb += 4) {
    float4 a4[4]; float2 a2[4];
    for (int kk = 0; kk < 4; ++kk) { a4[kk] = ck4[kb + kk]; a2[kk] = ck2[kb + kk]; }
    for (int kk = 0; kk < 4; ++kk) {
      for (int r = 0; r < 2; ++r) {
        float d = dist5s(f0[r], f1[r], f2[r], f3[r], f4[r], fq[r],
                         a4[kk].x, a4[kk].y, a4[kk].z, a4[kk].w, a2[kk].x, a2[kk].y);
        if (d < best[r]) { best[r] = d; bk[r] = kb + kk; }  // first-index wins
      }
    }
  }
  int* lb = labels + (size_t)b * HW;
  for (int r = 0; r < 2; ++r) lb[base + r * 256 + tid] = bk[r];
}

// ---------- embed: block = (b,p,q); LDS bins per (k,c); direct stores ----------
__global__ void __launch_bounds__(256) embed_kernel(
    const float* __restrict__ x, const int* __restrict__ labels,
    const float* __restrict__ A, float* __restrict__ out) {
  __shared__ float sk[NK * 3];
  int b = blockIdx.y;
  int p = blockIdx.x >> 4;
  int q = blockIdx.x & 15;
  int tid = threadIdx.x;
  for (int t = tid; t < NK * 3; t += 256) sk[t] = 0.0f;
  __syncthreads();

  // A[p,h] support: h in [14p-7, 14p+20] clipped
  int h0 = max(0, 14 * p - 7), h1 = min(IMGD - 1, 14 * p + 20);
  int w0 = max(0, 14 * q - 7), w1 = min(IMGD - 1, 14 * q + 20);
  int hl = h1 - h0 + 1, wl = w1 - w0 + 1;
  int n = hl * wl;

  const float* xb = x + (size_t)b * 3 * HW;
  const int* lb = labels + (size_t)b * HW;
  const float* Ap = A + p * IMGD;
  const float* Aq = A + q * IMGD;

  for (int idx = tid; idx < n; idx += 256) {
    int dh = idx / wl;
    int hh = h0 + dh;
    int ww = w0 + (idx - dh * wl);
    int i = hh * IMGD + ww;
    float wgt = Ap[hh] * Aq[ww];
    int k = lb[i];
    atomicAdd(&sk[k * 3 + 0], wgt * xb[i]);
    atomicAdd(&sk[k * 3 + 1], wgt * xb[HW + i]);
    atomicAdd(&sk[k * 3 + 2], wgt * xb[2 * HW + i]);
  }
  __syncthreads();

  float* outb = out + (size_t)b * OUT_PER_B;
  int base = p * 48 + q * 3;
  for (int t = tid; t < NK * 3; t += 256) {
    int k = t / 3, c = t - 3 * k;
    int f = k * 768 + base + c;           // flat [K,P,P,C] index
    outb[(f & 255) * 300 + (f >> 8)] = sk[t];  // view(B,300,256) + transpose
  }
}

extern "C" void kernel_launch(void* const* d_in, const int* in_sizes, int n_in,
                              void* d_out, int out_size, void* d_ws, size_t ws_size,
                              hipStream_t stream) {
  const float* x = (const float*)d_in[0];
  float* out = (float*)d_out;
  char* ws = (char*)d_ws;
  // ws layout:
  float* A        = (float*)(ws);              // 14336 B
  float* centers  = (float*)(ws + 16384);      // 16000 B
  float* c2g      = (float*)(ws + 49152);      // 3200 B
  int*   labels   = (int*)(ws + 90112);        // 1605632 B
  float* partials = (float*)(ws + 1703936);    // 8*100*6*131*4 = 2515200 B

  setup_kernel<<<24, 256, 0, stream>>>(x, A, centers, c2g);

  dim3 cgrid(66, NB);             // 66 blocks x 2 chunks = 131 chunks (+tail)
  for (int it = 0; it < 10; ++it) {
    iter_kernel<<<cgrid, 256, 0, stream>>>(x, centers, c2g, partials);
    combine_update_kernel<<<NB * NK, 128, 0, stream>>>(centers, partials, c2g);
  }
  dim3 agrid(98, NB);             // 98*512 = 50176 exact
  assign_kernel<<<agrid, 256, 0, stream>>>(x, centers, c2g, labels);

  dim3 egrid(256, NB);            // (p*16+q) x b
  embed_kernel<<<egrid, 256, 0, stream>>>(x, labels, A, out);
}

// Round 16
// 308.231 us; speedup vs baseline: 3.8119x; 1.1894x over previous
//
#include <hip/hip_runtime.h>
#include <math.h>

#define IMGD 224
#define HW 50176      // 224*224
#define NK 100
#define NB 8
#define OUT_PER_B 76800   // 100*16*16*3 = 300*256
#define NCHUNK 131        // OpenBLAS k-blocking of 50176: 129x384, 320, 320

// R12/R14 lesson: per-block device-scope fences serialize ~1.2-1.7 us of L2
// writeback EACH on gfx950 -> never reduce across blocks inside a kernel.
// Kernel boundary is the cheap coherence point.

// ratio = 10.0 / sqrt(224*224/100) in f64, rounded to f32 when numpy multiplies
// the f32 arange arrays by the weak python scalar.
static __device__ __forceinline__ float ratio_f32() {
  return (float)(10.0 / sqrt(224.0 * 224.0 / 100.0));
}

// distance op sequence — the single source of truth for bit-exactness:
// dot = fmul(f0,c0); fma(f1,c1); fma(f2,c2); fma(f3,c3); fma(f4,c4)
// d   = fsub(fadd(fsq, c2k), fmul(2, dot))
static __device__ __forceinline__ float dist5s(float f0, float f1, float f2,
                                               float f3, float f4, float fsq,
                                               float c0, float c1, float c2,
                                               float c3, float c4, float q) {
  float dot = __fmul_rn(f0, c0);
  dot = __fmaf_rn(f1, c1, dot);
  dot = __fmaf_rn(f2, c2, dot);
  dot = __fmaf_rn(f3, c3, dot);
  dot = __fmaf_rn(f4, c4, dot);
  return __fsub_rn(__fadd_rn(fsq, q), __fmul_rn(2.0f, dot));
}

// fsq = np.sum(feat*feat): rounded products, sequential adds, no FMA
static __device__ __forceinline__ float fsq5(float f0, float f1, float f2,
                                             float f3, float f4) {
  float s = __fmul_rn(f0, f0);
  s = __fadd_rn(s, __fmul_rn(f1, f1));
  s = __fadd_rn(s, __fmul_rn(f2, f2));
  s = __fadd_rn(s, __fmul_rn(f3, f3));
  s = __fadd_rn(s, __fmul_rn(f4, f4));
  return s;
}

// ---------- setup: blocks 0..15 build A; blocks 16..23 init centers+c2 ----------
__global__ void __launch_bounds__(256) setup_kernel(
    const float* __restrict__ x, float* __restrict__ A,
    float* __restrict__ centers, float* __restrict__ c2g) {
  int blk = blockIdx.x;
  int tid = threadIdx.x;
  if (blk < 16) {
    // resize matrix A[16][224], jax linear+antialias semantics
    __shared__ float red[256];
    int p = blk;
    float tri = 0.0f;
    if (tid < IMGD) {
      float center = (p + 0.5f) * 14.0f - 0.5f;
      float xd = fabsf(center - (float)tid) / 14.0f;
      tri = fmaxf(0.0f, 1.0f - xd);
    }
    red[tid] = tri;
    __syncthreads();
    for (int s = 128; s > 0; s >>= 1) {
      if (tid < s) red[tid] += red[tid + s];
      __syncthreads();
    }
    float Z = red[0];
    if (tid < IMGD) A[p * IMGD + tid] = tri / Z;
  } else {
    int b = blk - 16;
    int k = tid;
    if (k >= NK) return;
    int gy = k / 10, gx = k % 10;
    int cy = (int)((gy + 0.5) * 224.0 / 10.0);  // trunc like .astype(int32)
    int cx = (int)((gx + 0.5) * 224.0 / 10.0);
    int i = cy * IMGD + cx;
    const float ratio = ratio_f32();
    float c0 = x[((size_t)b * 3 + 0) * HW + i];
    float c1 = x[((size_t)b * 3 + 1) * HW + i];
    float c2 = x[((size_t)b * 3 + 2) * HW + i];
    float c3 = __fmul_rn((float)cy, ratio);
    float c4 = __fmul_rn((float)cx, ratio);
    float* c = centers + ((size_t)b * NK + k) * 5;
    c[0] = c0; c[1] = c1; c[2] = c2; c[3] = c3; c[4] = c4;
    // c2 = np.sum(centers*centers): rounded products, sequential adds
    float s = __fmul_rn(c0, c0);
    s = __fadd_rn(s, __fmul_rn(c1, c1));
    s = __fadd_rn(s, __fmul_rn(c2, c2));
    s = __fadd_rn(s, __fmul_rn(c3, c3));
    s = __fadd_rn(s, __fmul_rn(c4, c4));
    c2g[(size_t)b * NK + k] = s;
  }
}

// ---------- fused assign+partial: 2 chunks per 256-thread block ----------
// NEW: per-32px-group candidate pruning. For group box [f3min,f3max]x[f4min,
// f4max]: UB = min_k(dy_max^2+dx_max^2+3) (color^2<=3), keep k iff
// dy_min^2+dx_min^2 <= UB+1.0. Slack 1.0 >> f32 rounding (~1e-2) => excluded
// k's true distance strictly exceeds the group's best => argmin + ascending-k
// first-index tie semantics bit-preserved. ~20 of 100 candidates/group.
__global__ void __launch_bounds__(256) iter_kernel(
    const float* __restrict__ x, const float* __restrict__ centers,
    const float* __restrict__ c2g, float* __restrict__ partials) {
  __shared__ float4 ck4[NK];
  __shared__ float2 ck2[NK];
  __shared__ unsigned int mask[2 * NK * 12];
  __shared__ unsigned short ppk[2 * NK * 12];
  __shared__ float4 cval4[768];
  __shared__ float  cvalf[768];
  __shared__ int cnt[256];
  __shared__ int offx[256];
  __shared__ int wsum[4];
  __shared__ float gb[24][4];        // f3min,f3max,f4min,f4max per group
  __shared__ float ubpart[24][10];
  __shared__ float ubg[24];          // UB + slack
  __shared__ unsigned int candm[24][4];
  __shared__ unsigned char clist[24][104];
  __shared__ int clen[24];
  int blk = blockIdx.x;   // 0..65
  int b = blockIdx.y;
  int tid = threadIdx.x;
  int c0 = 2 * blk;
  bool has2 = (c0 < 130);
  int len0 = (c0 < 129) ? 384 : 320;
  int start0 = (c0 < 129) ? c0 * 384 : 49536 + (c0 - 129) * 320;
  int c1 = c0 + 1;
  int len1 = has2 ? ((c1 < 129) ? 384 : 320) : 0;
  int start1 = has2 ? ((c1 < 129) ? c1 * 384 : 49536 + (c1 - 129) * 320) : 0;
  int superlen = len0 + len1;

  const float* cb = centers + (size_t)b * NK * 5;
  const float* c2b = c2g + (size_t)b * NK;
  const float ratio = ratio_f32();
  if (tid < NK) {
    ck4[tid] = make_float4(cb[tid * 5 + 0], cb[tid * 5 + 1], cb[tid * 5 + 2], cb[tid * 5 + 3]);
    ck2[tid] = make_float2(cb[tid * 5 + 4], c2b[tid]);
  }
  for (int t = tid; t < 2 * NK * 12; t += 256) mask[t] = 0u;
  if (tid < 96) candm[tid / 4][tid & 3] = 0u;
  if (tid < 24) {
    // group bounds: group g covers tloc in [gg*32, gg*32+31] of chunk ch
    int ch = tid / 12, gg = tid - 12 * ch;
    int st = ch ? start1 : start0;
    int i0 = st + gg * 32, i1 = i0 + 31;
    int ymin = i0 / IMGD, ymax = i1 / IMGD;
    int cmin, cmax;
    if (ymin == ymax) { cmin = i0 - ymin * IMGD; cmax = i1 - ymax * IMGD; }
    else { cmin = 0; cmax = IMGD - 1; }   // row-wrap: widen (conservative)
    gb[tid][0] = __fmul_rn((float)ymin, ratio);
    gb[tid][1] = __fmul_rn((float)ymax, ratio);
    gb[tid][2] = __fmul_rn((float)cmin, ratio);
    gb[tid][3] = __fmul_rn((float)cmax, ratio);
  }
  __syncthreads();

  // UB phase: thread (g, kb) scans 10 centers
  if (tid < 240) {
    int g = tid / 10, kb = tid - 10 * g;
    float f3mn = gb[g][0], f3mx = gb[g][1], f4mn = gb[g][2], f4mx = gb[g][3];
    float mn = 3.4e38f;
    for (int k = kb * 10; k < kb * 10 + 10; ++k) {
      float c3 = ck4[k].w, c4 = ck2[k].x;
      float dy = fmaxf(fabsf(c3 - f3mn), fabsf(c3 - f3mx));
      float dx = fmaxf(fabsf(c4 - f4mn), fabsf(c4 - f4mx));
      float ub = dy * dy + dx * dx + 3.0f;
      mn = fminf(mn, ub);
    }
    ubpart[g][kb] = mn;
  }
  __syncthreads();
  if (tid < 24) {
    float mn = ubpart[tid][0];
    for (int j = 1; j < 10; ++j) mn = fminf(mn, ubpart[tid][j]);
    ubg[tid] = mn + 1.0f;   // slack >> all f32 rounding at these magnitudes
  }
  __syncthreads();

  // candidate flags (order-free atomicOr)
  if (tid < 240) {
    int g = tid / 10, kb = tid - 10 * g;
    float f3mn = gb[g][0], f3mx = gb[g][1], f4mn = gb[g][2], f4mx = gb[g][3];
    float lim = ubg[g];
    for (int k = kb * 10; k < kb * 10 + 10; ++k) {
      float c3 = ck4[k].w, c4 = ck2[k].x;
      float dy = fmaxf(0.0f, fmaxf(f3mn - c3, c3 - f3mx));
      float dx = fmaxf(0.0f, fmaxf(f4mn - c4, c4 - f4mx));
      if (dy * dy + dx * dx <= lim)
        atomicOr(&candm[g][k >> 5], 1u << (k & 31));
    }
  }
  __syncthreads();
  // dense ascending-k candidate lists
  if (tid < 24) {
    int len = 0;
    for (int w = 0; w < 4; ++w) {
      unsigned int m = candm[tid][w];
      while (m) {
        int j = __ffs(m) - 1;
        m &= m - 1;
        clist[tid][len++] = (unsigned char)(w * 32 + j);
      }
    }
    clen[tid] = len;
  }
  __syncthreads();

  const float* x0 = x + (size_t)b * 3 * HW;

  // 3 px/thread over the superchunk: t = tid, tid+256, tid+512 (ascending)
  float f0[3], f1[3], f2[3], f3[3], f4[3], fq[3], best[3];
  int bk[3], tloc[3], chnk[3];
  bool vld[3];
  for (int r = 0; r < 3; ++r) {
    int t = tid + r * 256;
    vld[r] = (t < superlen);
    int ch = (t >= len0) ? 1 : 0;
    int tl = t - ch * len0;
    if (!vld[r]) { ch = 0; tl = 0; }
    chnk[r] = ch; tloc[r] = tl;
    int i = (ch ? start1 : start0) + tl;
    int y = i / IMGD, xw = i - y * IMGD;
    f0[r] = x0[i]; f1[r] = x0[HW + i]; f2[r] = x0[2 * HW + i];
    f3[r] = __fmul_rn((float)y, ratio);
    f4[r] = __fmul_rn((float)xw, ratio);
    fq[r] = fsq5(f0[r], f1[r], f2[r], f3[r], f4[r]);
    best[r] = 3.4e38f; bk[r] = 0;
    // pruned distance loop: candidates ascending k (first-index tie safe)
    int g = ch * 12 + (tl >> 5);
    int n = clen[g];
    for (int j = 0; j < n; ++j) {
      int k = clist[g][j];
      float4 a4 = ck4[k];
      float2 a2 = ck2[k];
      float d = dist5s(f0[r], f1[r], f2[r], f3[r], f4[r], fq[r],
                       a4.x, a4.y, a4.z, a4.w, a2.x, a2.y);
      if (d < best[r]) { best[r] = d; bk[r] = k; }
    }
  }
  for (int r = 0; r < 3; ++r) {
    if (vld[r])
      atomicOr(&mask[chnk[r] * 1200 + bk[r] * 12 + (tloc[r] >> 5)],
               1u << (tloc[r] & 31));
  }
  __syncthreads();

  // per-(chunk,k) cumulative popcounts; u = chunk*100 + k
  int myCnt = 0;
  if (tid < 200) {
    int ch = tid / 100, k = tid - ch * 100;
    int s = 0;
    for (int g = 0; g < 12; ++g) {
      ppk[ch * 1200 + k * 12 + g] = (unsigned short)s;
      s += __popc(mask[ch * 1200 + k * 12 + g]);
    }
    myCnt = s;
  }
  cnt[tid] = myCnt;

  // inclusive prefix over 256 counts: shfl per wave + cross-wave fixup
  int v = myCnt;
  for (int d = 1; d < 64; d <<= 1) {
    int u = __shfl_up(v, d, 64);
    if ((tid & 63) >= d) v += u;
  }
  int wid = tid >> 6;
  if ((tid & 63) == 63) wsum[wid] = v;
  __syncthreads();
  if (wid >= 1) v += wsum[0];
  if (wid >= 2) v += wsum[1];
  if (wid >= 3) v += wsum[2];
  offx[tid] = v;
  __syncthreads();

  // stable VALUE scatter: chunk0 lands in [0,len0), chunk1 in [len0,superlen)
  for (int r = 0; r < 3; ++r) {
    if (vld[r]) {
      int u = chnk[r] * 100 + bk[r];
      int g = tloc[r] >> 5, j = tloc[r] & 31;
      unsigned int m = mask[chnk[r] * 1200 + bk[r] * 12 + g];
      int rank = ppk[chnk[r] * 1200 + bk[r] * 12 + g] +
                 __popc(m & ((1u << j) - 1u));
      int pos = offx[u] - cnt[u] + rank;
      cval4[pos] = make_float4(f0[r], f1[r], f2[r], f3[r]);
      cvalf[pos] = f4[r];
    }
  }
  __syncthreads();

  // scan: thread u walks its consecutive compacted range (ascending t)
  if (tid < 200 && (tid < 100 || has2)) {
    int ch = tid / 100, k = tid - ch * 100;
    int n = cnt[tid];
    int base = offx[tid] - n;
    float s0 = 0.f, s1 = 0.f, s2 = 0.f, s3 = 0.f, s4 = 0.f, s5 = 0.f;
    for (int m = 0; m < n; ++m) {
      float4 vv = cval4[base + m];
      float ww = cvalf[base + m];
      s0 = __fadd_rn(s0, vv.x);
      s1 = __fadd_rn(s1, vv.y);
      s2 = __fadd_rn(s2, vv.z);
      s3 = __fadd_rn(s3, vv.w);
      s4 = __fadd_rn(s4, ww);
      s5 += 1.0f;
    }
    // k-major layout [b][k][j][c]: combine reads contiguous
    int cc = ch ? c1 : c0;
    float* pp = partials + ((size_t)(b * NK + k) * 6) * NCHUNK + cc;
    pp[0 * NCHUNK] = s0; pp[1 * NCHUNK] = s1; pp[2 * NCHUNK] = s2;
    pp[3 * NCHUNK] = s3; pp[4 * NCHUNK] = s4; pp[5 * NCHUNK] = s5;
  }
}

// ---------- combine: one block per (b,k); LDS-staged 131-chains ----------
__global__ void __launch_bounds__(128) combine_update_kernel(
    float* __restrict__ centers, const float* __restrict__ partials,
    float* __restrict__ c2g) {
  __shared__ float st[6 * NCHUNK];
  __shared__ float sums[6];
  __shared__ float newc[5];
  int bk = blockIdx.x;                 // b*NK + k
  int tid = threadIdx.x;
  const float* base = partials + (size_t)bk * 6 * NCHUNK;
  for (int t = tid; t < 6 * NCHUNK; t += 128) st[t] = base[t];
  __syncthreads();
  if (tid < 6) {
    const float* row = st + tid * NCHUNK;
    float s = row[0];                  // C = 0 + chunk0 (exact)
    for (int c = 1; c < NCHUNK; ++c) s = __fadd_rn(s, row[c]);
    sums[tid] = s;
  }
  __syncthreads();
  float cntv = sums[5];
  float* cc = centers + (size_t)bk * 5;
  if (tid < 5) {
    float v;
    if (cntv > 0.0f) {                 // where(cnt>0, new, centers)
      float m = fmaxf(cntv, 1.0f);     // np.maximum(cnt,1.0): exact int in f32
      v = __fdiv_rn(sums[tid], m);
      cc[tid] = v;
    } else {
      v = cc[tid];                     // unchanged center
    }
    newc[tid] = v;
  }
  __syncthreads();
  if (tid == 0) {
    // c2 = sum(centers*centers): rounded products, sequential adds
    float t0 = __fmul_rn(newc[0], newc[0]);
    t0 = __fadd_rn(t0, __fmul_rn(newc[1], newc[1]));
    t0 = __fadd_rn(t0, __fmul_rn(newc[2], newc[2]));
    t0 = __fadd_rn(t0, __fmul_rn(newc[3], newc[3]));
    t0 = __fadd_rn(t0, __fmul_rn(newc[4], newc[4]));
    c2g[bk] = t0;
  }
}

// ---------- final full-image assignment: 2 px/thread, k-batched by 4 ----------
__global__ void __launch_bounds__(256) assign_kernel(
    const float* __restrict__ x, const float* __restrict__ centers,
    const float* __restrict__ c2g, int* __restrict__ labels) {
  __shared__ float4 ck4[NK];
  __shared__ float2 ck2[NK];
  int b = blockIdx.y;
  int tid = threadIdx.x;
  int base = blockIdx.x * 512;   // grid.x = 98 -> 98*512 = 50176 exact

  const float* cb = centers + (size_t)b * NK * 5;
  const float* c2b = c2g + (size_t)b * NK;
  for (int k = tid; k < NK; k += 256) {
    ck4[k] = make_float4(cb[k * 5 + 0], cb[k * 5 + 1], cb[k * 5 + 2], cb[k * 5 + 3]);
    ck2[k] = make_float2(cb[k * 5 + 4], c2b[k]);
  }
  __syncthreads();

  const float* x0 = x + (size_t)b * 3 * HW;
  const float ratio = ratio_f32();
  float f0[2], f1[2], f2[2], f3[2], f4[2], fq[2];
  float best[2]; int bk[2];
  for (int r = 0; r < 2; ++r) {
    int i = base + r * 256 + tid;   // coalesced
    int y = i / IMGD, xw = i - y * IMGD;
    f0[r] = x0[i]; f1[r] = x0[HW + i]; f2[r] = x0[2 * HW + i];
    f3[r] = __fmul_rn((float)y, ratio);
    f4[r] = __fmul_rn((float)xw, ratio);
    fq[r] = fsq5(f0[r], f1[r], f2[r], f3[r], f4[r]);
    best[r] = 3.4e38f; bk[r] = 0;
  }
  for (int kb = 0; kb < NK; kb += 4) {
    float4 a4[4]; float2 a2[4];
    for (int kk = 0; kk < 4; ++kk) { a4[kk] = ck4[kb + kk]; a2[kk] = ck2[kb + kk]; }
    for (int kk = 0; kk < 4; ++kk) {
      for (int r = 0; r < 2; ++r) {
        float d = dist5s(f0[r], f1[r], f2[r], f3[r], f4[r], fq[r],
                         a4[kk].x, a4[kk].y, a4[kk].z, a4[kk].w, a2[kk].x, a2[kk].y);
        if (d < best[r]) { best[r] = d; bk[r] = kb + kk; }  // first-index wins
      }
    }
  }
  int* lb = labels + (size_t)b * HW;
  for (int r = 0; r < 2; ++r) lb[base + r * 256 + tid] = bk[r];
}

// ---------- embed: block = (b,p,q); LDS bins per (k,c); direct stores ----------
__global__ void __launch_bounds__(256) embed_kernel(
    const float* __restrict__ x, const int* __restrict__ labels,
    const float* __restrict__ A, float* __restrict__ out) {
  __shared__ float sk[NK * 3];
  int b = blockIdx.y;
  int p = blockIdx.x >> 4;
  int q = blockIdx.x & 15;
  int tid = threadIdx.x;
  for (int t = tid; t < NK * 3; t += 256) sk[t] = 0.0f;
  __syncthreads();

  // A[p,h] support: h in [14p-7, 14p+20] clipped
  int h0 = max(0, 14 * p - 7), h1 = min(IMGD - 1, 14 * p + 20);
  int w0 = max(0, 14 * q - 7), w1 = min(IMGD - 1, 14 * q + 20);
  int hl = h1 - h0 + 1, wl = w1 - w0 + 1;
  int n = hl * wl;

  const float* xb = x + (size_t)b * 3 * HW;
  const int* lb = labels + (size_t)b * HW;
  const float* Ap = A + p * IMGD;
  const float* Aq = A + q * IMGD;

  for (int idx = tid; idx < n; idx += 256) {
    int dh = idx / wl;
    int hh = h0 + dh;
    int ww = w0 + (idx - dh * wl);
    int i = hh * IMGD + ww;
    float wgt = Ap[hh] * Aq[ww];
    int k = lb[i];
    atomicAdd(&sk[k * 3 + 0], wgt * xb[i]);
    atomicAdd(&sk[k * 3 + 1], wgt * xb[HW + i]);
    atomicAdd(&sk[k * 3 + 2], wgt * xb[2 * HW + i]);
  }
  __syncthreads();

  float* outb = out + (size_t)b * OUT_PER_B;
  int base = p * 48 + q * 3;
  for (int t = tid; t < NK * 3; t += 256) {
    int k = t / 3, c = t - 3 * k;
    int f = k * 768 + base + c;           // flat [K,P,P,C] index
    outb[(f & 255) * 300 + (f >> 8)] = sk[t];  // view(B,300,256) + transpose
  }
}

extern "C" void kernel_launch(void* const* d_in, const int* in_sizes, int n_in,
                              void* d_out, int out_size, void* d_ws, size_t ws_size,
                              hipStream_t stream) {
  const float* x = (const float*)d_in[0];
  float* out = (float*)d_out;
  char* ws = (char*)d_ws;
  // ws layout:
  float* A        = (float*)(ws);              // 14336 B
  float* centers  = (float*)(ws + 16384);      // 16000 B
  float* c2g      = (float*)(ws + 49152);      // 3200 B
  int*   labels   = (int*)(ws + 90112);        // 1605632 B
  float* partials = (float*)(ws + 1703936);    // 8*100*6*131*4 = 2515200 B

  setup_kernel<<<24, 256, 0, stream>>>(x, A, centers, c2g);

  dim3 cgrid(66, NB);             // 66 blocks x 2 chunks = 131 chunks (+tail)
  for (int it = 0; it < 10; ++it) {
    iter_kernel<<<cgrid, 256, 0, stream>>>(x, centers, c2g, partials);
    combine_update_kernel<<<NB * NK, 128, 0, stream>>>(centers, partials, c2g);
  }
  dim3 agrid(98, NB);             // 98*512 = 50176 exact
  assign_kernel<<<agrid, 256, 0, stream>>>(x, centers, c2g, labels);

  dim3 egrid(256, NB);            // (p*16+q) x b
  embed_kernel<<<egrid, 256, 0, stream>>>(x, labels, A, out);
}

// Round 17
// 298.832 us; speedup vs baseline: 3.9318x; 1.0315x over previous
//
#include <hip/hip_runtime.h>
#include <math.h>

#define IMGD 224
#define HW 50176      // 224*224
#define NK 100
#define NB 8
#define OUT_PER_B 76800   // 100*16*16*3 = 300*256
#define NCHUNK 131        // OpenBLAS k-blocking of 50176: 129x384, 320, 320

// R12/R14 lesson: per-block device-scope fences serialize ~1.2-1.7 us of L2
// writeback EACH on gfx950 -> never reduce across blocks inside a kernel.
// Kernel boundary is the cheap coherence point.

// ratio = 10.0 / sqrt(224*224/100) in f64, rounded to f32 when numpy multiplies
// the f32 arange arrays by the weak python scalar.
static __device__ __forceinline__ float ratio_f32() {
  return (float)(10.0 / sqrt(224.0 * 224.0 / 100.0));
}

// distance op sequence — the single source of truth for bit-exactness:
// dot = fmul(f0,c0); fma(f1,c1); fma(f2,c2); fma(f3,c3); fma(f4,c4)
// d   = fsub(fadd(fsq, c2k), fmul(2, dot))
static __device__ __forceinline__ float dist5s(float f0, float f1, float f2,
                                               float f3, float f4, float fsq,
                                               float c0, float c1, float c2,
                                               float c3, float c4, float q) {
  float dot = __fmul_rn(f0, c0);
  dot = __fmaf_rn(f1, c1, dot);
  dot = __fmaf_rn(f2, c2, dot);
  dot = __fmaf_rn(f3, c3, dot);
  dot = __fmaf_rn(f4, c4, dot);
  return __fsub_rn(__fadd_rn(fsq, q), __fmul_rn(2.0f, dot));
}

// fsq = np.sum(feat*feat): rounded products, sequential adds, no FMA
static __device__ __forceinline__ float fsq5(float f0, float f1, float f2,
                                             float f3, float f4) {
  float s = __fmul_rn(f0, f0);
  s = __fadd_rn(s, __fmul_rn(f1, f1));
  s = __fadd_rn(s, __fmul_rn(f2, f2));
  s = __fadd_rn(s, __fmul_rn(f3, f3));
  s = __fadd_rn(s, __fmul_rn(f4, f4));
  return s;
}

// ---------- setup: blocks 0..15 build A; blocks 16..23 init centers+c2 ----------
__global__ void __launch_bounds__(256) setup_kernel(
    const float* __restrict__ x, float* __restrict__ A,
    float* __restrict__ centers, float* __restrict__ c2g) {
  int blk = blockIdx.x;
  int tid = threadIdx.x;
  if (blk < 16) {
    // resize matrix A[16][224], jax linear+antialias semantics
    __shared__ float red[256];
    int p = blk;
    float tri = 0.0f;
    if (tid < IMGD) {
      float center = (p + 0.5f) * 14.0f - 0.5f;
      float xd = fabsf(center - (float)tid) / 14.0f;
      tri = fmaxf(0.0f, 1.0f - xd);
    }
    red[tid] = tri;
    __syncthreads();
    for (int s = 128; s > 0; s >>= 1) {
      if (tid < s) red[tid] += red[tid + s];
      __syncthreads();
    }
    float Z = red[0];
    if (tid < IMGD) A[p * IMGD + tid] = tri / Z;
  } else {
    int b = blk - 16;
    int k = tid;
    if (k >= NK) return;
    int gy = k / 10, gx = k % 10;
    int cy = (int)((gy + 0.5) * 224.0 / 10.0);  // trunc like .astype(int32)
    int cx = (int)((gx + 0.5) * 224.0 / 10.0);
    int i = cy * IMGD + cx;
    const float ratio = ratio_f32();
    float c0 = x[((size_t)b * 3 + 0) * HW + i];
    float c1 = x[((size_t)b * 3 + 1) * HW + i];
    float c2 = x[((size_t)b * 3 + 2) * HW + i];
    float c3 = __fmul_rn((float)cy, ratio);
    float c4 = __fmul_rn((float)cx, ratio);
    float* c = centers + ((size_t)b * NK + k) * 5;
    c[0] = c0; c[1] = c1; c[2] = c2; c[3] = c3; c[4] = c4;
    // c2 = np.sum(centers*centers): rounded products, sequential adds
    float s = __fmul_rn(c0, c0);
    s = __fadd_rn(s, __fmul_rn(c1, c1));
    s = __fadd_rn(s, __fmul_rn(c2, c2));
    s = __fadd_rn(s, __fmul_rn(c3, c3));
    s = __fadd_rn(s, __fmul_rn(c4, c4));
    c2g[(size_t)b * NK + k] = s;
  }
}

// ---------- fused assign+partial: 1 chunk per 128-thread block ----------
// Post-pruning the distance loop is cheap, so small blocks maximize
// residency (~18.5 KB LDS -> 8 blocks/CU) to hide the phase-pipeline
// barriers. Pixel global loads issued BEFORE the pruning phases to overlap.
// Pruning: UB = min_k(dy_max^2+dx_max^2+3), keep k iff dy_min^2+dx_min^2 <=
// UB+1.0 (slack >> f32 rounding) => argmin + ascending-k first-index ties
// bit-preserved. Compaction add chains ascending-pixel (bit-exact).
__global__ void __launch_bounds__(128, 4) iter_kernel(
    const float* __restrict__ x, const float* __restrict__ centers,
    const float* __restrict__ c2g, float* __restrict__ partials) {
  __shared__ float4 ck4[NK];
  __shared__ float2 ck2[NK];
  __shared__ unsigned int mask[NK * 12];
  __shared__ unsigned short ppk[NK * 12];
  __shared__ float4 cval4[384];
  __shared__ float  cvalf[384];
  __shared__ int cnt[128];
  __shared__ int offx[128];
  __shared__ int wtot;
  __shared__ float ubpart[12][10];
  __shared__ float ubg[12];
  __shared__ unsigned int candm[12][4];
  __shared__ unsigned char clist[12][104];
  __shared__ int clen[12];
  int c = blockIdx.x, b = blockIdx.y;
  int tid = threadIdx.x;
  int start = (c < 129) ? c * 384 : 49536 + (c - 129) * 320;
  int len   = (c < 129) ? 384 : 320;

  const float* cb = centers + (size_t)b * NK * 5;
  const float* c2b = c2g + (size_t)b * NK;
  const float ratio = ratio_f32();
  if (tid < NK) {
    ck4[tid] = make_float4(cb[tid * 5 + 0], cb[tid * 5 + 1], cb[tid * 5 + 2], cb[tid * 5 + 3]);
    ck2[tid] = make_float2(cb[tid * 5 + 4], c2b[tid]);
  }
  for (int t = tid; t < NK * 12; t += 128) mask[t] = 0u;
  if (tid < 48) candm[tid >> 2][tid & 3] = 0u;

  // pixel loads early (no LDS dependence) — overlap with pruning phases
  const float* x0 = x + (size_t)b * 3 * HW;
  float f0[3], f1[3], f2[3], f3[3], f4[3], fq[3];
  bool vld[3];
  for (int r = 0; r < 3; ++r) {
    int t = tid + r * 128;
    vld[r] = (t < len);
    int i = start + (vld[r] ? t : 0);
    int y = i / IMGD, xw = i - y * IMGD;
    f0[r] = x0[i]; f1[r] = x0[HW + i]; f2[r] = x0[2 * HW + i];
    f3[r] = __fmul_rn((float)y, ratio);
    f4[r] = __fmul_rn((float)xw, ratio);
    fq[r] = fsq5(f0[r], f1[r], f2[r], f3[r], f4[r]);
  }
  __syncthreads();

  // UB phase: thread (g,kb) scans 10 centers; group bounds in-register
  if (tid < 120) {
    int g = tid / 10, kb = tid - 10 * g;
    int i0 = start + g * 32, i1 = i0 + 31;
    int ymin = i0 / IMGD, ymax = i1 / IMGD;
    int cmin = (ymin == ymax) ? (i0 - ymin * IMGD) : 0;
    int cmax = (ymin == ymax) ? (i1 - ymax * IMGD) : (IMGD - 1);
    float f3mn = __fmul_rn((float)ymin, ratio);
    float f3mx = __fmul_rn((float)ymax, ratio);
    float f4mn = __fmul_rn((float)cmin, ratio);
    float f4mx = __fmul_rn((float)cmax, ratio);
    float mn = 3.4e38f;
    for (int k = kb * 10; k < kb * 10 + 10; ++k) {
      float c3 = ck4[k].w, c4 = ck2[k].x;
      float dy = fmaxf(fabsf(c3 - f3mn), fabsf(c3 - f3mx));
      float dx = fmaxf(fabsf(c4 - f4mn), fabsf(c4 - f4mx));
      mn = fminf(mn, dy * dy + dx * dx + 3.0f);
    }
    ubpart[g][kb] = mn;
  }
  __syncthreads();
  if (tid < 12) {
    float mn = ubpart[tid][0];
    for (int j = 1; j < 10; ++j) mn = fminf(mn, ubpart[tid][j]);
    ubg[tid] = mn + 1.0f;   // slack >> all f32 rounding at these magnitudes
  }
  __syncthreads();
  // candidate flags (order-free atomicOr)
  if (tid < 120) {
    int g = tid / 10, kb = tid - 10 * g;
    int i0 = start + g * 32, i1 = i0 + 31;
    int ymin = i0 / IMGD, ymax = i1 / IMGD;
    int cmin = (ymin == ymax) ? (i0 - ymin * IMGD) : 0;
    int cmax = (ymin == ymax) ? (i1 - ymax * IMGD) : (IMGD - 1);
    float f3mn = __fmul_rn((float)ymin, ratio);
    float f3mx = __fmul_rn((float)ymax, ratio);
    float f4mn = __fmul_rn((float)cmin, ratio);
    float f4mx = __fmul_rn((float)cmax, ratio);
    float lim = ubg[g];
    for (int k = kb * 10; k < kb * 10 + 10; ++k) {
      float c3 = ck4[k].w, c4 = ck2[k].x;
      float dy = fmaxf(0.0f, fmaxf(f3mn - c3, c3 - f3mx));
      float dx = fmaxf(0.0f, fmaxf(f4mn - c4, c4 - f4mx));
      if (dy * dy + dx * dx <= lim)
        atomicOr(&candm[g][k >> 5], 1u << (k & 31));
    }
  }
  __syncthreads();
  // dense ascending-k candidate lists
  if (tid < 12) {
    int len2 = 0;
    for (int w = 0; w < 4; ++w) {
      unsigned int m = candm[tid][w];
      while (m) {
        int j = __ffs(m) - 1;
        m &= m - 1;
        clist[tid][len2++] = (unsigned char)(w * 32 + j);
      }
    }
    clen[tid] = len2;
  }
  __syncthreads();

  // pruned distance loop: candidates ascending k (first-index ties safe)
  float best[3]; int bk[3];
  for (int r = 0; r < 3; ++r) {
    best[r] = 3.4e38f; bk[r] = 0;
    int t = tid + r * 128;
    int g = (t < 384) ? (t >> 5) : 0;
    int n = clen[g];
    for (int j = 0; j < n; ++j) {
      int k = clist[g][j];
      float4 a4 = ck4[k];
      float2 a2 = ck2[k];
      float d = dist5s(f0[r], f1[r], f2[r], f3[r], f4[r], fq[r],
                       a4.x, a4.y, a4.z, a4.w, a2.x, a2.y);
      if (d < best[r]) { best[r] = d; bk[r] = k; }
    }
  }
  for (int r = 0; r < 3; ++r) {
    int t = tid + r * 128;
    if (vld[r]) atomicOr(&mask[bk[r] * 12 + (t >> 5)], 1u << (t & 31));
  }
  __syncthreads();

  // per-k cumulative popcounts
  int myCnt = 0;
  if (tid < NK) {
    int s = 0;
    for (int g = 0; g < 12; ++g) {
      ppk[tid * 12 + g] = (unsigned short)s;
      s += __popc(mask[tid * 12 + g]);
    }
    myCnt = s;
  }
  cnt[tid] = myCnt;
  __syncthreads();

  // inclusive prefix over 128 counts: shfl per wave + cross-wave fixup
  int v = myCnt;
  for (int d = 1; d < 64; d <<= 1) {
    int u = __shfl_up(v, d, 64);
    if ((tid & 63) >= d) v += u;
  }
  if (tid == 63) wtot = v;
  __syncthreads();
  if (tid >= 64) v += wtot;
  offx[tid] = v;
  __syncthreads();

  // stable VALUE scatter: pos = (off[k]-cnt[k]) + rank_within_k(t)
  for (int r = 0; r < 3; ++r) {
    int t = tid + r * 128;
    if (vld[r]) {
      int g = t >> 5, j = t & 31;
      unsigned int m = mask[bk[r] * 12 + g];
      int rank = ppk[bk[r] * 12 + g] + __popc(m & ((1u << j) - 1u));
      int pos = offx[bk[r]] - cnt[bk[r]] + rank;
      cval4[pos] = make_float4(f0[r], f1[r], f2[r], f3[r]);
      cvalf[pos] = f4[r];
    }
  }
  __syncthreads();

  // scan: thread k walks its consecutive compacted range (ascending t)
  if (tid < NK) {
    int n = cnt[tid];
    int base = offx[tid] - n;
    float s0 = 0.f, s1 = 0.f, s2 = 0.f, s3 = 0.f, s4 = 0.f, s5 = 0.f;
    for (int m = 0; m < n; ++m) {
      float4 vv = cval4[base + m];
      float ww = cvalf[base + m];
      s0 = __fadd_rn(s0, vv.x);
      s1 = __fadd_rn(s1, vv.y);
      s2 = __fadd_rn(s2, vv.z);
      s3 = __fadd_rn(s3, vv.w);
      s4 = __fadd_rn(s4, ww);
      s5 += 1.0f;
    }
    // k-major layout [b][k][j][c]: combine reads contiguous
    float* pp = partials + ((size_t)(b * NK + tid) * 6) * NCHUNK + c;
    pp[0 * NCHUNK] = s0; pp[1 * NCHUNK] = s1; pp[2 * NCHUNK] = s2;
    pp[3 * NCHUNK] = s3; pp[4 * NCHUNK] = s4; pp[5 * NCHUNK] = s5;
  }
}

// ---------- combine: one block per (b,k); LDS-staged 131-chains ----------
__global__ void __launch_bounds__(128) combine_update_kernel(
    float* __restrict__ centers, const float* __restrict__ partials,
    float* __restrict__ c2g) {
  __shared__ float st[6 * NCHUNK];
  __shared__ float sums[6];
  __shared__ float newc[5];
  int bk = blockIdx.x;                 // b*NK + k
  int tid = threadIdx.x;
  const float* base = partials + (size_t)bk * 6 * NCHUNK;
  for (int t = tid; t < 6 * NCHUNK; t += 128) st[t] = base[t];
  __syncthreads();
  if (tid < 6) {
    const float* row = st + tid * NCHUNK;
    float s = row[0];                  // C = 0 + chunk0 (exact)
    for (int c = 1; c < NCHUNK; ++c) s = __fadd_rn(s, row[c]);
    sums[tid] = s;
  }
  __syncthreads();
  float cntv = sums[5];
  float* cc = centers + (size_t)bk * 5;
  if (tid < 5) {
    float v;
    if (cntv > 0.0f) {                 // where(cnt>0, new, centers)
      float m = fmaxf(cntv, 1.0f);     // np.maximum(cnt,1.0): exact int in f32
      v = __fdiv_rn(sums[tid], m);
      cc[tid] = v;
    } else {
      v = cc[tid];                     // unchanged center
    }
    newc[tid] = v;
  }
  __syncthreads();
  if (tid == 0) {
    // c2 = sum(centers*centers): rounded products, sequential adds
    float t0 = __fmul_rn(newc[0], newc[0]);
    t0 = __fadd_rn(t0, __fmul_rn(newc[1], newc[1]));
    t0 = __fadd_rn(t0, __fmul_rn(newc[2], newc[2]));
    t0 = __fadd_rn(t0, __fmul_rn(newc[3], newc[3]));
    t0 = __fadd_rn(t0, __fmul_rn(newc[4], newc[4]));
    c2g[bk] = t0;
  }
}

// ---------- final full-image assignment: 2 px/thread, k-batched by 4 ----------
__global__ void __launch_bounds__(256) assign_kernel(
    const float* __restrict__ x, const float* __restrict__ centers,
    const float* __restrict__ c2g, int* __restrict__ labels) {
  __shared__ float4 ck4[NK];
  __shared__ float2 ck2[NK];
  int b = blockIdx.y;
  int tid = threadIdx.x;
  int base = blockIdx.x * 512;   // grid.x = 98 -> 98*512 = 50176 exact

  const float* cb = centers + (size_t)b * NK * 5;
  const float* c2b = c2g + (size_t)b * NK;
  for (int k = tid; k < NK; k += 256) {
    ck4[k] = make_float4(cb[k * 5 + 0], cb[k * 5 + 1], cb[k * 5 + 2], cb[k * 5 + 3]);
    ck2[k] = make_float2(cb[k * 5 + 4], c2b[k]);
  }
  __syncthreads();

  const float* x0 = x + (size_t)b * 3 * HW;
  const float ratio = ratio_f32();
  float f0[2], f1[2], f2[2], f3[2], f4[2], fq[2];
  float best[2]; int bk[2];
  for (int r = 0; r < 2; ++r) {
    int i = base + r * 256 + tid;   // coalesced
    int y = i / IMGD, xw = i - y * IMGD;
    f0[r] = x0[i]; f1[r] = x0[HW + i]; f2[r] = x0[2 * HW + i];
    f3[r] = __fmul_rn((float)y, ratio);
    f4[r] = __fmul_rn((float)xw, ratio);
    fq[r] = fsq5(f0[r], f1[r], f2[r], f3[r], f4[r]);
    best[r] = 3.4e38f; bk[r] = 0;
  }
  for (int kb = 0; kb < NK; kb += 4) {
    float4 a4[4]; float2 a2[4];
    for (int kk = 0; kk < 4; ++kk) { a4[kk] = ck4[kb + kk]; a2[kk] = ck2[kb + kk]; }
    for (int kk = 0; kk < 4; ++kk) {
      for (int r = 0; r < 2; ++r) {
        float d = dist5s(f0[r], f1[r], f2[r], f3[r], f4[r], fq[r],
                         a4[kk].x, a4[kk].y, a4[kk].z, a4[kk].w, a2[kk].x, a2[kk].y);
        if (d < best[r]) { best[r] = d; bk[r] = kb + kk; }  // first-index wins
      }
    }
  }
  int* lb = labels + (size_t)b * HW;
  for (int r = 0; r < 2; ++r) lb[base + r * 256 + tid] = bk[r];
}

// ---------- embed: block = (b,p,q); LDS bins per (k,c); direct stores ----------
__global__ void __launch_bounds__(256) embed_kernel(
    const float* __restrict__ x, const int* __restrict__ labels,
    const float* __restrict__ A, float* __restrict__ out) {
  __shared__ float sk[NK * 3];
  int b = blockIdx.y;
  int p = blockIdx.x >> 4;
  int q = blockIdx.x & 15;
  int tid = threadIdx.x;
  for (int t = tid; t < NK * 3; t += 256) sk[t] = 0.0f;
  __syncthreads();

  // A[p,h] support: h in [14p-7, 14p+20] clipped
  int h0 = max(0, 14 * p - 7), h1 = min(IMGD - 1, 14 * p + 20);
  int w0 = max(0, 14 * q - 7), w1 = min(IMGD - 1, 14 * q + 20);
  int hl = h1 - h0 + 1, wl = w1 - w0 + 1;
  int n = hl * wl;

  const float* xb = x + (size_t)b * 3 * HW;
  const int* lb = labels + (size_t)b * HW;
  const float* Ap = A + p * IMGD;
  const float* Aq = A + q * IMGD;

  for (int idx = tid; idx < n; idx += 256) {
    int dh = idx / wl;
    int hh = h0 + dh;
    int ww = w0 + (idx - dh * wl);
    int i = hh * IMGD + ww;
    float wgt = Ap[hh] * Aq[ww];
    int k = lb[i];
    atomicAdd(&sk[k * 3 + 0], wgt * xb[i]);
    atomicAdd(&sk[k * 3 + 1], wgt * xb[HW + i]);
    atomicAdd(&sk[k * 3 + 2], wgt * xb[2 * HW + i]);
  }
  __syncthreads();

  float* outb = out + (size_t)b * OUT_PER_B;
  int base = p * 48 + q * 3;
  for (int t = tid; t < NK * 3; t += 256) {
    int k = t / 3, c = t - 3 * k;
    int f = k * 768 + base + c;           // flat [K,P,P,C] index
    outb[(f & 255) * 300 + (f >> 8)] = sk[t];  // view(B,300,256) + transpose
  }
}

extern "C" void kernel_launch(void* const* d_in, const int* in_sizes, int n_in,
                              void* d_out, int out_size, void* d_ws, size_t ws_size,
                              hipStream_t stream) {
  const float* x = (const float*)d_in[0];
  float* out = (float*)d_out;
  char* ws = (char*)d_ws;
  // ws layout:
  float* A        = (float*)(ws);              // 14336 B
  float* centers  = (float*)(ws + 16384);      // 16000 B
  float* c2g      = (float*)(ws + 49152);      // 3200 B
  int*   labels   = (int*)(ws + 90112);        // 1605632 B
  float* partials = (float*)(ws + 1703936);    // 8*100*6*131*4 = 2515200 B

  setup_kernel<<<24, 256, 0, stream>>>(x, A, centers, c2g);

  dim3 cgrid(NCHUNK, NB);         // 131 x 8 — 1048 blocks, ~8 blocks/CU
  for (int it = 0; it < 10; ++it) {
    iter_kernel<<<cgrid, 128, 0, stream>>>(x, centers, c2g, partials);
    combine_update_kernel<<<NB * NK, 128, 0, stream>>>(centers, partials, c2g);
  }
  dim3 agrid(98, NB);             // 98*512 = 50176 exact
  assign_kernel<<<agrid, 256, 0, stream>>>(x, centers, c2g, labels);

  dim3 egrid(256, NB);            // (p*16+q) x b
  embed_kernel<<<egrid, 256, 0, stream>>>(x, labels, A, out);
}